// Round 11
// baseline (379.635 us; speedup 1.0000x reference)
//
#include <hip/hip_runtime.h>

typedef _Float16 h8 __attribute__((ext_vector_type(8)));
typedef _Float16 h4 __attribute__((ext_vector_type(4)));
typedef _Float16 h2 __attribute__((ext_vector_type(2)));
typedef float    f4 __attribute__((ext_vector_type(4)));

// K=16 MFMA, fragment-major operands (R7), VALU-trimmed (R9: 169us).
// R10 lesson: 6-wave split reached 62% occupancy, but waves_per_eu(8,8)
// min-8 forced VGPR to 32 -> 186MB spill. R11: min-4 budget (128 regs,
// R9's proven no-spill regime); body needs ~55 so expect <=64 -> 8/EU.
#define MFMA4(a,b,c) __builtin_amdgcn_mfma_f32_16x16x16f16((a),(b),(c),0,0,0)

#define NSEQ  5200
#define NNODE 325
#define LE    96
#define LD    144
#define OUTL  48
#define NTHR  384   // 6 waves: wave w owns enc tile w; waves 0-2 own dec tiles,
                    // waves 3-5 take dec-FFN chunks 2-3 (R1/R10-proven exchange)

// K LDS: frag-major [st][kt2][lane][8] (identity producer->consumer lane map).
// Vt: [d][kv] stride 104 (kv 0..95; R5 lesson: stride must cover 96).
#define SVT   104

#define K_OFF    0
#define VT_OFF   6144             // 6 st * 1024 halves
#define MISC_OFF 12800            // + 64*104 = 6656 halves
#define LDS_HALVES 13288          // 26,576 B

// decoder-FFN exchange overlays (K/Vt dead after B6a):
#define X_OFF    0                // 3 tiles x 1024 halves: post-attn xd
#define P_OFF_H  3072             // fp32 partials: 3 x [64][17] (pad 17)

// ws: 10 frag-major 64x64 mats + dc1 + dc2, then 128 fp32 pre-scaled q-biases
#define WSQ(i)   ((i)*4096)
#define WS_DC1   40960
#define WS_DC2   57344
#define WS_BQ    73728            // fp32: ebq*0.125 [64], dbq*0.125 [64]
#define WS_TOTAL 73728

struct Params {
  const float* x_enc; const float* x_dec;
  const float* enc_conv_w; const float* dec_conv_w;
  const float* eWq; const float* ebq; const float* eWk; const float* ebk;
  const float* eWv; const float* ebv; const float* eWo; const float* ebo;
  const float* ec1_w; const float* ec1_b; const float* ec2_w; const float* ec2_b;
  const float* en1_g; const float* en1_b; const float* en2_g; const float* en2_b;
  const float* dWq; const float* dbq; const float* dWk; const float* dbk;
  const float* dWv; const float* dbv; const float* dWo; const float* dbo;
  const float* dc1_w; const float* dc1_b; const float* dc2_w; const float* dc2_b;
  const float* dn2_g; const float* dn2_b; const float* dn3_g; const float* dn3_b;
  const float* proj_w; const float* proj_b;
  float* out;
};

__device__ __forceinline__ float wave_sum(float v){
  v += __shfl_xor(v, 32, 64); v += __shfl_xor(v, 16, 64);
  v += __shfl_xor(v,  8, 64); v += __shfl_xor(v,  4, 64);
  v += __shfl_xor(v,  2, 64); v += __shfl_xor(v,  1, 64);
  return v;
}
__device__ __forceinline__ float q_sum(float v){
  v += __shfl_xor(v, 16, 64); v += __shfl_xor(v, 32, 64); return v;
}

__device__ __forceinline__ h4 lo4(h8 v){ return __builtin_shufflevector(v, v, 0,1,2,3); }
__device__ __forceinline__ h4 hi4(h8 v){ return __builtin_shufflevector(v, v, 4,5,6,7); }
__device__ __forceinline__ h8 cat8(h4 a, h4 b){ return __builtin_shufflevector(a, b, 0,1,2,3,4,5,6,7); }

__device__ __forceinline__ h4 pk4(f4 v){
  h2 a = __builtin_bit_cast(h2, __builtin_amdgcn_cvt_pkrtz(v[0], v[1]));
  h2 b = __builtin_bit_cast(h2, __builtin_amdgcn_cvt_pkrtz(v[2], v[3]));
  return __builtin_shufflevector(a, b, 0,1,2,3);
}
__device__ __forceinline__ h4 relu_pk(f4 v){
  f4 r;
  #pragma unroll
  for (int i = 0; i < 4; ++i) r[i] = fmaxf(v[i], 0.f);
  return pk4(r);
}

// single-tile Y^T = A @ t + bias (bias -> MFMA C-init)
__device__ __forceinline__ void mm64T(const _Float16* __restrict__ A,
                                      const h4 t[4], f4 out[4], int lane,
                                      const float* __restrict__ bias, int d0){
  #pragma unroll
  for (int nt = 0; nt < 4; ++nt){
    const _Float16* ar = A + (nt*128 + lane)*8;
    h8 w0 = *(const h8*)(ar);
    h8 w1 = *(const h8*)(ar + 512);
    f4 c = *(const f4*)(bias + nt*16 + d0);
    c = MFMA4(lo4(w0), t[0], c);
    c = MFMA4(hi4(w0), t[1], c);
    c = MFMA4(lo4(w1), t[2], c);
    c = MFMA4(hi4(w1), t[3], c);
    out[nt] = c;
  }
}

// LN: single-pass sum/sumsq + fused fma normalize + packed cvt
__device__ __forceinline__ void lnT(const f4 vf[4], h4 xt[4],
        const float* __restrict__ g_, const float* __restrict__ b_, int q){
  const int d0 = 4*q;
  float s = 0.f, s2 = 0.f;
  #pragma unroll
  for (int nt = 0; nt < 4; ++nt)
    #pragma unroll
    for (int i = 0; i < 4; ++i){ float v = vf[nt][i]; s += v; s2 = fmaf(v, v, s2); }
  s = q_sum(s); s2 = q_sum(s2);
  float mu = s * (1.f/64.f);
  float rs = rsqrtf(fmaxf(s2 * (1.f/64.f) - mu*mu, 0.f) + 1e-5f);
  #pragma unroll
  for (int nt = 0; nt < 4; ++nt){
    f4 g4 = *(const f4*)(g_ + nt*16 + d0);
    f4 b4 = *(const f4*)(b_ + nt*16 + d0);
    f4 o;
    #pragma unroll
    for (int i = 0; i < 4; ++i){
      float sc = g4[i]*rs;
      o[i] = fmaf(vf[nt][i], sc, fmaf(-mu, sc, b4[i]));
    }
    xt[nt] = pk4(o);
  }
}

// scores: frag-major K, max-free softmax, DEFERRED normalization
__device__ __forceinline__ float scoresT(const h4 qt[4], const _Float16* Kf,
                                         h4 pt[6], int lane){
  f4 s[6];
  #pragma unroll
  for (int st = 0; st < 6; ++st){
    const _Float16* kr = Kf + st*1024 + lane*8;
    h8 w0 = *(const h8*)(kr);
    h8 w1 = *(const h8*)(kr + 512);
    f4 cc = {0.f,0.f,0.f,0.f};
    cc = MFMA4(lo4(w0), qt[0], cc);
    cc = MFMA4(hi4(w0), qt[1], cc);
    cc = MFMA4(lo4(w1), qt[2], cc);
    cc = MFMA4(hi4(w1), qt[3], cc);
    s[st] = cc;
  }
  float sm = 0.f;
  #pragma unroll
  for (int st = 0; st < 6; ++st)
    #pragma unroll
    for (int i = 0; i < 4; ++i){ float e = __expf(s[st][i]); s[st][i] = e; sm += e; }
  sm = q_sum(sm);
  #pragma unroll
  for (int st = 0; st < 6; ++st) pt[st] = pk4(s[st]);
  return 1.f/sm;
}

// single-tile attention + residual + LN (no Wo prefetch: TLP hides L2 latency)
__device__ __forceinline__ void attnT(h4 xt[4], const _Float16* Kf, const _Float16* Vt,
        const _Float16* __restrict__ Wqt, const float* __restrict__ qb,
        const _Float16* __restrict__ Wot, const float* __restrict__ bo,
        const float* __restrict__ g_, const float* __restrict__ b_,
        int lane, int m, int q){
  const int d0 = 4*q;
  f4 c[4];
  mm64T(Wqt, xt, c, lane, qb, d0);
  h4 qt[4];
  #pragma unroll
  for (int nt = 0; nt < 4; ++nt) qt[nt] = pk4(c[nt]);
  h4 pt[6];
  float r_ = scoresT(qt, Kf, pt, lane);
  h4 ot[4];
  #pragma unroll
  for (int nt = 0; nt < 4; ++nt){
    const _Float16* vr = Vt + (nt*16+m)*SVT + 4*q;
    f4 c0 = {0.f,0.f,0.f,0.f}, c1 = {0.f,0.f,0.f,0.f};
    #pragma unroll
    for (int st = 0; st < 3; ++st)
      c0 = MFMA4(*(const h4*)(vr + st*16), pt[st], c0);
    #pragma unroll
    for (int st = 3; st < 6; ++st)
      c1 = MFMA4(*(const h4*)(vr + st*16), pt[st], c1);
    ot[nt] = pk4((c0 + c1) * r_);
  }
  f4 vf[4];
  #pragma unroll
  for (int nt = 0; nt < 4; ++nt){
    const _Float16* ar = Wot + (nt*128 + lane)*8;
    h8 w0 = *(const h8*)(ar);
    h8 w1 = *(const h8*)(ar + 512);
    f4 cc = *(const f4*)(bo + nt*16 + d0);
    cc = MFMA4(lo4(w0), ot[0], cc);
    cc = MFMA4(hi4(w0), ot[1], cc);
    cc = MFMA4(lo4(w1), ot[2], cc);
    cc = MFMA4(hi4(w1), ot[3], cc);
    #pragma unroll
    for (int i = 0; i < 4; ++i) vf[nt][i] = cc[i] + (float)xt[nt][i];
  }
  lnT(vf, xt, g_, b_, q);
}

// single-tile FFN d->d + residual + LN
__device__ __forceinline__ void ffnT(h4 xt[4],
        const _Float16* __restrict__ W1t, const float* __restrict__ b1,
        const _Float16* __restrict__ W2t, const float* __restrict__ b2,
        const float* __restrict__ g_, const float* __restrict__ b_,
        int lane, int q){
  const int d0 = 4*q;
  f4 c[4];
  mm64T(W1t, xt, c, lane, b1, d0);
  h4 ht[4];
  #pragma unroll
  for (int nt = 0; nt < 4; ++nt) ht[nt] = relu_pk(c[nt]);
  f4 y[4];
  mm64T(W2t, ht, y, lane, b2, d0);
  f4 vf[4];
  #pragma unroll
  for (int nt = 0; nt < 4; ++nt){
    #pragma unroll
    for (int i = 0; i < 4; ++i) vf[nt][i] = y[nt][i] + (float)xt[nt][i];
  }
  lnT(vf, xt, g_, b_, q);
}

// single-tile K/V build: K frag-major b128 stores; Vt scatter stride 104.
__device__ __forceinline__ void kvT(const h4 xt[4], int r0,
        _Float16* Kf, _Float16* Vt,
        const _Float16* __restrict__ Wkt, const float* __restrict__ bk,
        const _Float16* __restrict__ Wvt, const float* __restrict__ bv,
        int lane, int m, int q){
  const int d0 = 4*q;
  f4 c[4];
  mm64T(Wkt, xt, c, lane, bk, d0);
  {
    h4 o[4];
    #pragma unroll
    for (int nt = 0; nt < 4; ++nt) o[nt] = pk4(c[nt]);
    const int st = r0 >> 4;
    *(h8*)(Kf + st*1024       + lane*8) = cat8(o[0], o[1]);
    *(h8*)(Kf + st*1024 + 512 + lane*8) = cat8(o[2], o[3]);
  }
  mm64T(Wvt, xt, c, lane, bv, d0);
  #pragma unroll
  for (int nt = 0; nt < 4; ++nt){
    #pragma unroll
    for (int i = 0; i < 4; ++i)
      Vt[(nt*16 + d0 + i)*SVT + r0 + m] = (_Float16)c[nt][i];
  }
}

// T-form conv (taps pre-mean-subtracted at callsite): 3 fma per element
__device__ __forceinline__ void convT(h4 xt[4], const float* __restrict__ cw,
                                      float xl, float xc, float xr, int q){
  const int d0 = 4*q;
  #pragma unroll
  for (int nt = 0; nt < 4; ++nt){
    const float* w = cw + 3*(nt*16 + d0);
    f4 o;
    #pragma unroll
    for (int i = 0; i < 4; ++i)
      o[i] = fmaf(w[3*i], xl, fmaf(w[3*i+1], xc, w[3*i+2]*xr));
    xt[nt] = pk4(o);
  }
}

// ---- weight prep: fp32 -> fp16 FRAG-MAJOR; Wq*0.125; prescaled fp32 q-biases ----
__global__ void prep_weights(Params p, _Float16* ws){
  const float* sq[10] = {p.eWq, p.eWk, p.eWv, p.eWo, p.ec1_w, p.ec2_w,
                         p.dWq, p.dWk, p.dWv, p.dWo};
  for (int idx = blockIdx.x*blockDim.x + threadIdx.x; idx < WS_TOTAL;
       idx += gridDim.x*blockDim.x){
    int r  = idx & 4095;
    int h  = r & 7, l = (r>>3) & 63, kt2 = (r>>9) & 1, nt = r>>10;
    int m  = l & 15, q = l >> 4;
    int orow = nt*16 + m;
    int kk   = kt2*32 + (h>>2)*16 + q*4 + (h&3);
    float v;
    if (idx < WS_DC1){
      int mi = idx >> 12;
      float sc = (mi == 0 || mi == 6) ? 0.125f : 1.f;
      v = sq[mi][kk*64 + orow] * sc;
    } else if (idx < WS_DC2){
      int cc = (idx - WS_DC1) >> 12;
      v = p.dc1_w[kk*256 + cc*64 + orow];
    } else {
      int cc = (idx - WS_DC2) >> 12;
      v = p.dc2_w[(cc*64 + kk)*64 + orow];
    }
    ws[idx] = (_Float16)v;
  }
  int t0 = blockIdx.x*blockDim.x + threadIdx.x;
  if (t0 < 128){
    float* qb = (float*)(ws + WS_BQ);
    qb[t0] = (t0 < 64 ? p.ebq[t0] : p.dbq[t0 - 64]) * 0.125f;
  }
}

// waves_per_eu(4,8): 128-reg allocator budget (R9's proven no-spill regime);
// body needs ~55 -> expect <=64 actual -> up to 8 waves/EU. Residency then
// thread-capped: 5 blocks x 6 waves = 30 waves/CU.
// R10 lesson: min-8 forced 32 VGPR -> 186MB spill. Tripwire: WRITE_SIZE 7.755MB.
__global__ void __launch_bounds__(NTHR)
__attribute__((amdgpu_waves_per_eu(4, 8)))
GraphTransformer_90237262889124_kernel(Params p, const _Float16* __restrict__ ws)
{
  __shared__ __align__(16) _Float16 lds[LDS_HALVES];
  _Float16* Kf   = lds + K_OFF;
  _Float16* Vt   = lds + VT_OFF;
  float*    serE = (float*)(lds + MISC_OFF);
  float*    serD = serE + 96;
  float*    stat = serD + 144;

  const int tid = threadIdx.x, lane = tid & 63, wave = tid >> 6;
  const int m = lane & 15, q = lane >> 4;
  const int d0 = 4*q;
  const int b = blockIdx.x / NNODE, n = blockIdx.x % NNODE;

  const _Float16* eWq_t = ws + WSQ(0);
  const _Float16* eWk_t = ws + WSQ(1);
  const _Float16* eWv_t = ws + WSQ(2);
  const _Float16* eWo_t = ws + WSQ(3);
  const _Float16* ec1_t = ws + WSQ(4);
  const _Float16* ec2_t = ws + WSQ(5);
  const _Float16* dWq_t = ws + WSQ(6);
  const _Float16* dWk_t = ws + WSQ(7);
  const _Float16* dWv_t = ws + WSQ(8);
  const _Float16* dWo_t = ws + WSQ(9);
  const _Float16* dc1f  = ws + WS_DC1;
  const _Float16* dc2f  = ws + WS_DC2;
  const float* qbE = (const float*)(ws + WS_BQ);
  const float* qbD = qbE + 64;

  // ---- P0: series loads ----
  if (tid < LE) serE[tid] = p.x_enc[(b*LE + tid)*NNODE + n];
  if (tid >= 128 && tid < 128 + LD)
    serD[tid - 128] = p.x_dec[(b*LD + (tid - 128))*NNODE + n];
  __syncthreads();                       // B1
  // ---- P1: means ----
  if (wave == 0){
    float v = serE[lane] + (lane < 32 ? serE[64 + lane] : 0.f);
    float s = wave_sum(v);
    if (lane == 0) stat[0] = s * (1.f/96.f);
  }
  if (wave == 1){
    float v = (lane < OUTL) ? serD[lane] : 0.f;
    float s = wave_sum(v);
    if (lane == 0) stat[1] = s * (1.f/48.f);
  }
  __syncthreads();                       // B2

  const int rT = wave * 16;              // this wave's enc tile rows
  h4 xt[4];
  // ---- P2: enc conv + enc K/V (one tile per wave) ----
  {
    const float mu = stat[0];
    const int l  = rT + m;
    const int lm = l ? l - 1 : LE - 1;
    const int lp = (l == LE-1) ? 0 : l + 1;
    convT(xt, p.enc_conv_w, serE[lm]-mu, serE[l]-mu, serE[lp]-mu, q);
    kvT(xt, rT, Kf, Vt, eWk_t, p.ebk, eWv_t, p.ebv, lane, m, q);
  }
  __syncthreads();                       // B3: enc K/V visible
  // ---- P3: enc attention + FFN (all 6 waves, single tile) ----
  attnT(xt, Kf, Vt, eWq_t, qbE, eWo_t, p.ebo, p.en1_g, p.en1_b, lane, m, q);
  ffnT(xt, ec1_t, p.ec1_b, ec2_t, p.ec2_b, p.en2_g, p.en2_b, lane, q);
  __syncthreads();                       // B4: enc attn reads done
  // ---- P4: dec conv (waves 0-2) + dec cross K/V from enc_out (all waves) ----
  h4 xd[4];
  if (wave < 3){
    const float mu = stat[1];
    const int gr = 96 + rT + m;          // rows 96..143
    float xl = serD[gr-1];
    float xc = serD[gr];
    float xr = (gr == LD-1) ? (serD[0] - mu) : serD[gr+1];
    convT(xd, p.dec_conv_w, xl, xc, xr, q);
  }
  kvT(xt, rT, Kf, Vt, dWk_t, p.dbk, dWv_t, p.dbv, lane, m, q);
  __syncthreads();                       // B5: dec K/V visible
  // ---- P5a: dec cross-attn (waves 0-2, one tile each) ----
  if (wave < 3)
    attnT(xd, Kf, Vt, dWq_t, qbD, dWo_t, p.dbo, p.dn2_g, p.dn2_b, lane, m, q);
  __syncthreads();                       // B6a: all K/Vt reads done -> overlays safe
  // ---- exchange post-attn x so waves 3-5 can take FFN chunks 2,3 ----
  if (wave < 3){
    #pragma unroll
    for (int nt = 0; nt < 4; ++nt)
      *(h4*)(lds + X_OFF + wave*1024 + nt*256 + lane*4) = xd[nt];
  }
  __syncthreads();                       // B6b: x visible
  h4 xf[4];
  if (wave >= 3){
    #pragma unroll
    for (int nt = 0; nt < 4; ++nt)
      xf[nt] = *(const h4*)(lds + X_OFF + (wave-3)*1024 + nt*256 + lane*4);
  } else {
    #pragma unroll
    for (int nt = 0; nt < 4; ++nt) xf[nt] = xd[nt];
  }
  // ---- P5b: dec FFN d->4d->d, 2 hidden chunks per wave ----
  f4 acc[4];
  #pragma unroll
  for (int nt = 0; nt < 4; ++nt){
    if (wave < 3) acc[nt] = *(const f4*)(p.dc2_b + nt*16 + d0);
    else          acc[nt] = f4{0.f,0.f,0.f,0.f};
  }
  const int cB = (wave < 3) ? 0 : 2;
  for (int cc2 = cB; cc2 < cB + 2; ++cc2){
    f4 hh[4];
    mm64T(dc1f + cc2*4096, xf, hh, lane, p.dc1_b + cc2*64, d0);
    h4 ht[4];
    #pragma unroll
    for (int nt = 0; nt < 4; ++nt) ht[nt] = relu_pk(hh[nt]);
    #pragma unroll
    for (int nt = 0; nt < 4; ++nt){
      const _Float16* ar = dc2f + cc2*4096 + (nt*128 + lane)*8;
      h8 w0 = *(const h8*)(ar);
      h8 w1 = *(const h8*)(ar + 512);
      acc[nt] = MFMA4(lo4(w0), ht[0], acc[nt]);
      acc[nt] = MFMA4(hi4(w0), ht[1], acc[nt]);
      acc[nt] = MFMA4(lo4(w1), ht[2], acc[nt]);
      acc[nt] = MFMA4(hi4(w1), ht[3], acc[nt]);
    }
  }
  float* Pex = (float*)(lds + P_OFF_H);
  if (wave >= 3){
    float* Pp = Pex + (wave - 3)*1088;   // [64 d][17] fp32, pad 17
    #pragma unroll
    for (int nt = 0; nt < 4; ++nt)
      #pragma unroll
      for (int i = 0; i < 4; ++i)
        Pp[(nt*16 + d0 + i)*17 + m] = acc[nt][i];
  }
  __syncthreads();                       // B7: partials visible
  // ---- P5c: reduce partials + LN(dn3) + proj + enc-mean (waves 0-2) ----
  if (wave < 3){
    const float* Pp = Pex + wave*1088;
    f4 vf[4];
    #pragma unroll
    for (int nt = 0; nt < 4; ++nt){
      #pragma unroll
      for (int i = 0; i < 4; ++i)
        vf[nt][i] = acc[nt][i] + Pp[(nt*16 + d0 + i)*17 + m] + (float)xd[nt][i];
    }
    float s = 0.f, s2 = 0.f;
    #pragma unroll
    for (int nt = 0; nt < 4; ++nt)
      #pragma unroll
      for (int i = 0; i < 4; ++i){ float v = vf[nt][i]; s += v; s2 = fmaf(v, v, s2); }
    s = q_sum(s); s2 = q_sum(s2);
    float mu = s * (1.f/64.f);
    float rs = rsqrtf(fmaxf(s2 * (1.f/64.f) - mu*mu, 0.f) + 1e-5f);
    float pp = 0.f;
    #pragma unroll
    for (int nt = 0; nt < 4; ++nt){
      f4 g4 = *(const f4*)(p.dn3_g + nt*16 + d0);
      f4 b4 = *(const f4*)(p.dn3_b + nt*16 + d0);
      f4 w4 = *(const f4*)(p.proj_w + nt*16 + d0);
      #pragma unroll
      for (int i = 0; i < 4; ++i)
        pp += ((vf[nt][i]-mu)*rs*g4[i] + b4[i]) * w4[i];
    }
    pp = q_sum(pp);
    if (q == 0)
      p.out[(b*OUTL + rT + m)*NNODE + n] = pp + p.proj_b[0] + stat[0];
  }
}

extern "C" void kernel_launch(void* const* d_in, const int* in_sizes, int n_in,
                              void* d_out, int out_size, void* d_ws, size_t ws_size,
                              hipStream_t stream) {
  Params p;
  p.x_enc = (const float*)d_in[0];  p.x_dec = (const float*)d_in[1];
  p.enc_conv_w = (const float*)d_in[4];  p.dec_conv_w = (const float*)d_in[5];
  p.eWq = (const float*)d_in[6];   p.ebq = (const float*)d_in[7];
  p.eWk = (const float*)d_in[8];   p.ebk = (const float*)d_in[9];
  p.eWv = (const float*)d_in[10];  p.ebv = (const float*)d_in[11];
  p.eWo = (const float*)d_in[12];  p.ebo = (const float*)d_in[13];
  p.ec1_w = (const float*)d_in[14]; p.ec1_b = (const float*)d_in[15];
  p.ec2_w = (const float*)d_in[16]; p.ec2_b = (const float*)d_in[17];
  p.en1_g = (const float*)d_in[18]; p.en1_b = (const float*)d_in[19];
  p.en2_g = (const float*)d_in[20]; p.en2_b = (const float*)d_in[21];
  p.dWq = (const float*)d_in[22];  p.dbq = (const float*)d_in[23];
  p.dWk = (const float*)d_in[24];  p.dbk = (const float*)d_in[25];
  p.dWv = (const float*)d_in[26];  p.dbv = (const float*)d_in[27];
  p.dWo = (const float*)d_in[28];  p.dbo = (const float*)d_in[29];
  p.dc1_w = (const float*)d_in[30]; p.dc1_b = (const float*)d_in[31];
  p.dc2_w = (const float*)d_in[32]; p.dc2_b = (const float*)d_in[33];
  p.dn2_g = (const float*)d_in[34]; p.dn2_b = (const float*)d_in[35];
  p.dn3_g = (const float*)d_in[36]; p.dn3_b = (const float*)d_in[37];
  p.proj_w = (const float*)d_in[38]; p.proj_b = (const float*)d_in[39];
  p.out = (float*)d_out;

  _Float16* ws = (_Float16*)d_ws;
  prep_weights<<<144, 512, 0, stream>>>(p, ws);
  GraphTransformer_90237262889124_kernel<<<NSEQ, NTHR, 0, stream>>>(p, ws);
}

// Round 13
// 277.080 us; speedup vs baseline: 1.3701x; 1.3701x over previous
//
#include <hip/hip_runtime.h>

typedef _Float16 h8 __attribute__((ext_vector_type(8)));
typedef _Float16 h4 __attribute__((ext_vector_type(4)));
typedef _Float16 h2 __attribute__((ext_vector_type(2)));
typedef float    f4 __attribute__((ext_vector_type(4)));

// K=16 MFMA, all operands fragment-major (R7), VALU-trimmed (R9: 169us).
// R10/R11 lesson: 6-wave single-tile split loses (same pipe work, more stall;
// occupancy does NOT rise with resources -> TLP not a lever; ILP/wave is).
// This is the R9 kernel: dual-tile 3-wave, bias via MFMA C-init, deferred
// softmax norm, packed cvt.
#define MFMA4(a,b,c) __builtin_amdgcn_mfma_f32_16x16x16f16((a),(b),(c),0,0,0)

#define NSEQ  5200
#define NNODE 325
#define LE    96
#define LD    144
#define OUTL  48
#define NTHR  192   // 3 waves; wave w owns enc tiles w and w+3, dec tile w

// K LDS: frag-major [st][kt2][lane][8] (identity producer->consumer lane map).
// Vt: [d][kv] stride 104 (kv 0..95; R5 lesson: stride must cover 96).
#define SVT   104

#define K_OFF    0
#define VT_OFF   6144             // 6 st * 1024 halves
#define MISC_OFF 12800            // + 64*104 = 6656 halves
#define LDS_HALVES 13288          // 26,576 B

// ws: 10 frag-major 64x64 mats + dc1 + dc2, then 128 fp32 pre-scaled q-biases
#define WSQ(i)   ((i)*4096)
#define WS_DC1   40960
#define WS_DC2   57344
#define WS_BQ    73728            // fp32: ebq*0.125 [64], dbq*0.125 [64]
#define WS_TOTAL 73728

struct Params {
  const float* x_enc; const float* x_dec;
  const float* enc_conv_w; const float* dec_conv_w;
  const float* eWq; const float* ebq; const float* eWk; const float* ebk;
  const float* eWv; const float* ebv; const float* eWo; const float* ebo;
  const float* ec1_w; const float* ec1_b; const float* ec2_w; const float* ec2_b;
  const float* en1_g; const float* en1_b; const float* en2_g; const float* en2_b;
  const float* dWq; const float* dbq; const float* dWk; const float* dbk;
  const float* dWv; const float* dbv; const float* dWo; const float* dbo;
  const float* dc1_w; const float* dc1_b; const float* dc2_w; const float* dc2_b;
  const float* dn2_g; const float* dn2_b; const float* dn3_g; const float* dn3_b;
  const float* proj_w; const float* proj_b;
  float* out;
};

__device__ __forceinline__ float wave_sum(float v){
  v += __shfl_xor(v, 32, 64); v += __shfl_xor(v, 16, 64);
  v += __shfl_xor(v,  8, 64); v += __shfl_xor(v,  4, 64);
  v += __shfl_xor(v,  2, 64); v += __shfl_xor(v,  1, 64);
  return v;
}
__device__ __forceinline__ float q_sum(float v){
  v += __shfl_xor(v, 16, 64); v += __shfl_xor(v, 32, 64); return v;
}

__device__ __forceinline__ h4 lo4(h8 v){ return __builtin_shufflevector(v, v, 0,1,2,3); }
__device__ __forceinline__ h4 hi4(h8 v){ return __builtin_shufflevector(v, v, 4,5,6,7); }
__device__ __forceinline__ h8 cat8(h4 a, h4 b){ return __builtin_shufflevector(a, b, 0,1,2,3,4,5,6,7); }

// packed f32x4 -> f16x4 (2x v_cvt_pkrtz instead of 4x v_cvt_f16_f32)
__device__ __forceinline__ h4 pk4(f4 v){
  h2 a = __builtin_bit_cast(h2, __builtin_amdgcn_cvt_pkrtz(v[0], v[1]));
  h2 b = __builtin_bit_cast(h2, __builtin_amdgcn_cvt_pkrtz(v[2], v[3]));
  return __builtin_shufflevector(a, b, 0,1,2,3);
}
__device__ __forceinline__ h4 relu_pk(f4 v){
  f4 r;
  #pragma unroll
  for (int i = 0; i < 4; ++i) r[i] = fmaxf(v[i], 0.f);
  return pk4(r);
}

// dual-tile Y^T = A @ t + bias (bias -> MFMA C-init; saves post-adds)
__device__ __forceinline__ void mm64T2(const _Float16* __restrict__ A,
                                       const h4 ta[4], const h4 tb[4],
                                       f4 oa[4], f4 ob[4], int lane,
                                       const float* __restrict__ bias, int d0){
  #pragma unroll
  for (int nt = 0; nt < 4; ++nt){
    const _Float16* ar = A + (nt*128 + lane)*8;
    h8 w0 = *(const h8*)(ar);
    h8 w1 = *(const h8*)(ar + 512);
    f4 b4 = *(const f4*)(bias + nt*16 + d0);
    f4 ca = b4, cb = b4;
    ca = MFMA4(lo4(w0), ta[0], ca);  cb = MFMA4(lo4(w0), tb[0], cb);
    ca = MFMA4(hi4(w0), ta[1], ca);  cb = MFMA4(hi4(w0), tb[1], cb);
    ca = MFMA4(lo4(w1), ta[2], ca);  cb = MFMA4(lo4(w1), tb[2], cb);
    ca = MFMA4(hi4(w1), ta[3], ca);  cb = MFMA4(hi4(w1), tb[3], cb);
    oa[nt] = ca; ob[nt] = cb;
  }
}
// single-tile variant (decoder)
__device__ __forceinline__ void mm64T(const _Float16* __restrict__ A,
                                      const h4 t[4], f4 out[4], int lane,
                                      const float* __restrict__ bias, int d0){
  #pragma unroll
  for (int nt = 0; nt < 4; ++nt){
    const _Float16* ar = A + (nt*128 + lane)*8;
    h8 w0 = *(const h8*)(ar);
    h8 w1 = *(const h8*)(ar + 512);
    f4 c = *(const f4*)(bias + nt*16 + d0);
    c = MFMA4(lo4(w0), t[0], c);
    c = MFMA4(hi4(w0), t[1], c);
    c = MFMA4(lo4(w1), t[2], c);
    c = MFMA4(hi4(w1), t[3], c);
    out[nt] = c;
  }
}

// LN: single-pass sum/sumsq + fused fma normalize + packed cvt
__device__ __forceinline__ void lnT(const f4 vf[4], h4 xt[4],
        const float* __restrict__ g_, const float* __restrict__ b_, int q){
  const int d0 = 4*q;
  float s = 0.f, s2 = 0.f;
  #pragma unroll
  for (int nt = 0; nt < 4; ++nt)
    #pragma unroll
    for (int i = 0; i < 4; ++i){ float v = vf[nt][i]; s += v; s2 = fmaf(v, v, s2); }
  s = q_sum(s); s2 = q_sum(s2);
  float mu = s * (1.f/64.f);
  float rs = rsqrtf(fmaxf(s2 * (1.f/64.f) - mu*mu, 0.f) + 1e-5f);
  #pragma unroll
  for (int nt = 0; nt < 4; ++nt){
    f4 g4 = *(const f4*)(g_ + nt*16 + d0);
    f4 b4 = *(const f4*)(b_ + nt*16 + d0);
    f4 o;
    #pragma unroll
    for (int i = 0; i < 4; ++i){
      float sc = g4[i]*rs;
      o[i] = fmaf(vf[nt][i], sc, fmaf(-mu, sc, b4[i]));
    }
    xt[nt] = pk4(o);
  }
}

// scores: frag-major K, max-free softmax with DEFERRED normalization --
// returns r = 1/sum; pt holds unnormalized exp(s) (e^s in [0.7,1.4], fp16-safe).
__device__ __forceinline__ float scoresT(const h4 qt[4], const _Float16* Kf,
                                         h4 pt[6], int lane){
  f4 s[6];
  #pragma unroll
  for (int st = 0; st < 6; ++st){
    const _Float16* kr = Kf + st*1024 + lane*8;
    h8 w0 = *(const h8*)(kr);
    h8 w1 = *(const h8*)(kr + 512);
    f4 cc = {0.f,0.f,0.f,0.f};
    cc = MFMA4(lo4(w0), qt[0], cc);
    cc = MFMA4(hi4(w0), qt[1], cc);
    cc = MFMA4(lo4(w1), qt[2], cc);
    cc = MFMA4(hi4(w1), qt[3], cc);
    s[st] = cc;
  }
  float sm = 0.f;
  #pragma unroll
  for (int st = 0; st < 6; ++st)
    #pragma unroll
    for (int i = 0; i < 4; ++i){ float e = __expf(s[st][i]); s[st][i] = e; sm += e; }
  sm = q_sum(sm);
  #pragma unroll
  for (int st = 0; st < 6; ++st) pt[st] = pk4(s[st]);
  return 1.f/sm;
}

// dual-tile attention + residual + LN (q-bias prescaled fp32 in ws)
__device__ __forceinline__ void attnT2(h4 xA[4], h4 xB[4],
        const _Float16* Kf, const _Float16* Vt,
        const _Float16* __restrict__ Wqt, const float* __restrict__ qb,
        const _Float16* __restrict__ Wot, const float* __restrict__ bo,
        const float* __restrict__ g_, const float* __restrict__ b_,
        int lane, int m, int q){
  const int d0 = 4*q;
  f4 cA[4], cB[4];
  mm64T2(Wqt, xA, xB, cA, cB, lane, qb, d0);
  h4 qA[4], qB[4];
  #pragma unroll
  for (int nt = 0; nt < 4; ++nt){ qA[nt] = pk4(cA[nt]); qB[nt] = pk4(cB[nt]); }
  h4 pA[6], pB[6];
  float rA_ = scoresT(qA, Kf, pA, lane);
  float rB_ = scoresT(qB, Kf, pB, lane);
  // Prefetch Wo A-frags (global latency hides under PV)
  h8 wo0[4], wo1[4];
  #pragma unroll
  for (int nt = 0; nt < 4; ++nt){
    const _Float16* ar = Wot + (nt*128 + lane)*8;
    wo0[nt] = *(const h8*)(ar);
    wo1[nt] = *(const h8*)(ar + 512);
  }
  // O^T = V^T @ P^T (unnormalized), r folded into output pack
  h4 otA[4], otB[4];
  #pragma unroll
  for (int nt = 0; nt < 4; ++nt){
    const _Float16* vr = Vt + (nt*16+m)*SVT + 4*q;
    f4 ca0 = {0.f,0.f,0.f,0.f}, cb0 = {0.f,0.f,0.f,0.f};
    f4 ca1 = {0.f,0.f,0.f,0.f}, cb1 = {0.f,0.f,0.f,0.f};
    #pragma unroll
    for (int st = 0; st < 3; ++st){
      h4 v = *(const h4*)(vr + st*16);
      ca0 = MFMA4(v, pA[st], ca0);
      cb0 = MFMA4(v, pB[st], cb0);
    }
    #pragma unroll
    for (int st = 3; st < 6; ++st){
      h4 v = *(const h4*)(vr + st*16);
      ca1 = MFMA4(v, pA[st], ca1);
      cb1 = MFMA4(v, pB[st], cb1);
    }
    otA[nt] = pk4((ca0 + ca1) * rA_);
    otB[nt] = pk4((cb0 + cb1) * rB_);
  }
  // O proj (bias C-init) + residual + LN
  f4 vfA[4], vfB[4];
  #pragma unroll
  for (int nt = 0; nt < 4; ++nt){
    f4 b4 = *(const f4*)(bo + nt*16 + d0);
    f4 ca = b4, cb = b4;
    ca = MFMA4(lo4(wo0[nt]), otA[0], ca);  cb = MFMA4(lo4(wo0[nt]), otB[0], cb);
    ca = MFMA4(hi4(wo0[nt]), otA[1], ca);  cb = MFMA4(hi4(wo0[nt]), otB[1], cb);
    ca = MFMA4(lo4(wo1[nt]), otA[2], ca);  cb = MFMA4(lo4(wo1[nt]), otB[2], cb);
    ca = MFMA4(hi4(wo1[nt]), otA[3], ca);  cb = MFMA4(hi4(wo1[nt]), otB[3], cb);
    #pragma unroll
    for (int i = 0; i < 4; ++i){
      vfA[nt][i] = ca[i] + (float)xA[nt][i];
      vfB[nt][i] = cb[i] + (float)xB[nt][i];
    }
  }
  lnT(vfA, xA, g_, b_, q);
  lnT(vfB, xB, g_, b_, q);
}

// single-tile attention (decoder)
__device__ __forceinline__ void attnT(h4 xt[4], const _Float16* Kf, const _Float16* Vt,
        const _Float16* __restrict__ Wqt, const float* __restrict__ qb,
        const _Float16* __restrict__ Wot, const float* __restrict__ bo,
        const float* __restrict__ g_, const float* __restrict__ b_,
        int lane, int m, int q){
  const int d0 = 4*q;
  f4 c[4];
  mm64T(Wqt, xt, c, lane, qb, d0);
  h4 qt[4];
  #pragma unroll
  for (int nt = 0; nt < 4; ++nt) qt[nt] = pk4(c[nt]);
  h4 pt[6];
  float r_ = scoresT(qt, Kf, pt, lane);
  h8 wo0[4], wo1[4];
  #pragma unroll
  for (int nt = 0; nt < 4; ++nt){
    const _Float16* ar = Wot + (nt*128 + lane)*8;
    wo0[nt] = *(const h8*)(ar);
    wo1[nt] = *(const h8*)(ar + 512);
  }
  h4 ot[4];
  #pragma unroll
  for (int nt = 0; nt < 4; ++nt){
    const _Float16* vr = Vt + (nt*16+m)*SVT + 4*q;
    f4 c0 = {0.f,0.f,0.f,0.f}, c1 = {0.f,0.f,0.f,0.f};
    #pragma unroll
    for (int st = 0; st < 3; ++st)
      c0 = MFMA4(*(const h4*)(vr + st*16), pt[st], c0);
    #pragma unroll
    for (int st = 3; st < 6; ++st)
      c1 = MFMA4(*(const h4*)(vr + st*16), pt[st], c1);
    ot[nt] = pk4((c0 + c1) * r_);
  }
  f4 vf[4];
  #pragma unroll
  for (int nt = 0; nt < 4; ++nt){
    f4 cc = *(const f4*)(bo + nt*16 + d0);
    cc = MFMA4(lo4(wo0[nt]), ot[0], cc);
    cc = MFMA4(hi4(wo0[nt]), ot[1], cc);
    cc = MFMA4(lo4(wo1[nt]), ot[2], cc);
    cc = MFMA4(hi4(wo1[nt]), ot[3], cc);
    #pragma unroll
    for (int i = 0; i < 4; ++i) vf[nt][i] = cc[i] + (float)xt[nt][i];
  }
  lnT(vf, xt, g_, b_, q);
}

// dual-tile FFN d->d + residual + LN (biases C-init)
__device__ __forceinline__ void ffnT2(h4 xA[4], h4 xB[4],
        const _Float16* __restrict__ W1t, const float* __restrict__ b1,
        const _Float16* __restrict__ W2t, const float* __restrict__ b2,
        const float* __restrict__ g_, const float* __restrict__ b_,
        int lane, int q){
  const int d0 = 4*q;
  f4 cA[4], cB[4];
  mm64T2(W1t, xA, xB, cA, cB, lane, b1, d0);
  h4 hA[4], hB[4];
  #pragma unroll
  for (int nt = 0; nt < 4; ++nt){ hA[nt] = relu_pk(cA[nt]); hB[nt] = relu_pk(cB[nt]); }
  f4 yA[4], yB[4];
  mm64T2(W2t, hA, hB, yA, yB, lane, b2, d0);
  f4 vfA[4], vfB[4];
  #pragma unroll
  for (int nt = 0; nt < 4; ++nt){
    #pragma unroll
    for (int i = 0; i < 4; ++i){
      vfA[nt][i] = yA[nt][i] + (float)xA[nt][i];
      vfB[nt][i] = yB[nt][i] + (float)xB[nt][i];
    }
  }
  lnT(vfA, xA, g_, b_, q);
  lnT(vfB, xB, g_, b_, q);
}

// dual-tile K/V build (biases C-init): K frag-major b128 stores; Vt scatter.
__device__ __forceinline__ void kvT2(const h4 xA[4], const h4 xB[4], int rA, int rB,
        _Float16* Kf, _Float16* Vt,
        const _Float16* __restrict__ Wkt, const float* __restrict__ bk,
        const _Float16* __restrict__ Wvt, const float* __restrict__ bv,
        int lane, int m, int q){
  const int d0 = 4*q;
  f4 cA[4], cB[4];
  mm64T2(Wkt, xA, xB, cA, cB, lane, bk, d0);
  {
    h4 oA[4], oB[4];
    #pragma unroll
    for (int nt = 0; nt < 4; ++nt){ oA[nt] = pk4(cA[nt]); oB[nt] = pk4(cB[nt]); }
    const int stA = rA >> 4, stB = rB >> 4;
    *(h8*)(Kf + stA*1024       + lane*8) = cat8(oA[0], oA[1]);
    *(h8*)(Kf + stA*1024 + 512 + lane*8) = cat8(oA[2], oA[3]);
    *(h8*)(Kf + stB*1024       + lane*8) = cat8(oB[0], oB[1]);
    *(h8*)(Kf + stB*1024 + 512 + lane*8) = cat8(oB[2], oB[3]);
  }
  mm64T2(Wvt, xA, xB, cA, cB, lane, bv, d0);
  #pragma unroll
  for (int nt = 0; nt < 4; ++nt){
    #pragma unroll
    for (int i = 0; i < 4; ++i){
      Vt[(nt*16 + d0 + i)*SVT + rA + m] = (_Float16)cA[nt][i];
      Vt[(nt*16 + d0 + i)*SVT + rB + m] = (_Float16)cB[nt][i];
    }
  }
}

// T-form conv (taps pre-mean-subtracted at callsite): 3 fma per element
__device__ __forceinline__ void convT(h4 xt[4], const float* __restrict__ cw,
                                      float xl, float xc, float xr, int q){
  const int d0 = 4*q;
  #pragma unroll
  for (int nt = 0; nt < 4; ++nt){
    const float* w = cw + 3*(nt*16 + d0);
    f4 o;
    #pragma unroll
    for (int i = 0; i < 4; ++i)
      o[i] = fmaf(w[3*i], xl, fmaf(w[3*i+1], xc, w[3*i+2]*xr));
    xt[nt] = pk4(o);
  }
}

// ---- weight prep: fp32 -> fp16 FRAG-MAJOR; Wq*0.125; prescaled fp32 q-biases ----
__global__ void prep_weights(Params p, _Float16* ws){
  const float* sq[10] = {p.eWq, p.eWk, p.eWv, p.eWo, p.ec1_w, p.ec2_w,
                         p.dWq, p.dWk, p.dWv, p.dWo};
  for (int idx = blockIdx.x*blockDim.x + threadIdx.x; idx < WS_TOTAL;
       idx += gridDim.x*blockDim.x){
    int r  = idx & 4095;
    int h  = r & 7, l = (r>>3) & 63, kt2 = (r>>9) & 1, nt = r>>10;
    int m  = l & 15, q = l >> 4;
    int orow = nt*16 + m;
    int kk   = kt2*32 + (h>>2)*16 + q*4 + (h&3);
    float v;
    if (idx < WS_DC1){
      int mi = idx >> 12;
      float sc = (mi == 0 || mi == 6) ? 0.125f : 1.f;
      v = sq[mi][kk*64 + orow] * sc;
    } else if (idx < WS_DC2){
      int cc = (idx - WS_DC1) >> 12;
      v = p.dc1_w[kk*256 + cc*64 + orow];
    } else {
      int cc = (idx - WS_DC2) >> 12;
      v = p.dc2_w[(cc*64 + kk)*64 + orow];
    }
    ws[idx] = (_Float16)v;
  }
  int t0 = blockIdx.x*blockDim.x + threadIdx.x;
  if (t0 < 128){
    float* qb = (float*)(ws + WS_BQ);
    qb[t0] = (t0 < 64 ? p.ebq[t0] : p.dbq[t0 - 64]) * 0.125f;
  }
}

// waves_per_eu(3,4): ~128-reg allocator budget (R9-verified no-spill, 68 VGPR).
__global__ void __launch_bounds__(NTHR)
__attribute__((amdgpu_waves_per_eu(3, 4)))
GraphTransformer_90237262889124_kernel(Params p, const _Float16* __restrict__ ws)
{
  __shared__ __align__(16) _Float16 lds[LDS_HALVES];
  _Float16* Kf   = lds + K_OFF;
  _Float16* Vt   = lds + VT_OFF;
  float*    serE = (float*)(lds + MISC_OFF);
  float*    serD = serE + 96;
  float*    stat = serD + 144;

  const int tid = threadIdx.x, lane = tid & 63, wave = tid >> 6;
  const int m = lane & 15, q = lane >> 4;
  const int d0 = 4*q;
  const int b = blockIdx.x / NNODE, n = blockIdx.x % NNODE;

  const _Float16* eWq_t = ws + WSQ(0);
  const _Float16* eWk_t = ws + WSQ(1);
  const _Float16* eWv_t = ws + WSQ(2);
  const _Float16* eWo_t = ws + WSQ(3);
  const _Float16* ec1_t = ws + WSQ(4);
  const _Float16* ec2_t = ws + WSQ(5);
  const _Float16* dWq_t = ws + WSQ(6);
  const _Float16* dWk_t = ws + WSQ(7);
  const _Float16* dWv_t = ws + WSQ(8);
  const _Float16* dWo_t = ws + WSQ(9);
  const _Float16* dc1f  = ws + WS_DC1;
  const _Float16* dc2f  = ws + WS_DC2;
  const float* qbE = (const float*)(ws + WS_BQ);
  const float* qbD = qbE + 64;

  // ---- P0: series loads ----
  if (tid < LE) serE[tid] = p.x_enc[(b*LE + tid)*NNODE + n];
  if (tid >= 48) serD[tid - 48] = p.x_dec[(b*LD + (tid - 48))*NNODE + n];
  __syncthreads();                       // B1
  // ---- P1: means ----
  if (wave == 0){
    float v = serE[lane] + (lane < 32 ? serE[64 + lane] : 0.f);
    float s = wave_sum(v);
    if (lane == 0) stat[0] = s * (1.f/96.f);
  }
  if (wave == 1){
    float v = (lane < OUTL) ? serD[lane] : 0.f;
    float s = wave_sum(v);
    if (lane == 0) stat[1] = s * (1.f/48.f);
  }
  __syncthreads();                       // B2

  const int rA = wave * 16;              // enc tile A rows
  const int rB = (wave + 3) * 16;        // enc tile B rows
  h4 xA[4], xB[4];
  // ---- P2: enc conv (both tiles) + enc K/V ----
  {
    const float mu = stat[0];
    int lA = rA + m;
    int lmA = lA ? lA-1 : LE-1;
    int lpA = (lA == LE-1) ? 0 : lA+1;
    convT(xA, p.enc_conv_w, serE[lmA]-mu, serE[lA]-mu, serE[lpA]-mu, q);
    int lB = rB + m;
    int lmB = lB - 1;                    // rB >= 48, never wraps low
    int lpB = (lB == LE-1) ? 0 : lB+1;
    convT(xB, p.enc_conv_w, serE[lmB]-mu, serE[lB]-mu, serE[lpB]-mu, q);
    kvT2(xA, xB, rA, rB, Kf, Vt, eWk_t, p.ebk, eWv_t, p.ebv, lane, m, q);
  }
  __syncthreads();                       // B3: enc K/V visible
  // ---- P3: enc attention + FFN (dual-tile) ----
  attnT2(xA, xB, Kf, Vt, eWq_t, qbE, eWo_t, p.ebo, p.en1_g, p.en1_b, lane, m, q);
  ffnT2(xA, xB, ec1_t, p.ec1_b, ec2_t, p.ec2_b, p.en2_g, p.en2_b, lane, q);
  __syncthreads();                       // B4: all attn reads done
  // ---- P4: dec cross K/V from enc_out; dec conv hoisted ----
  h4 xt[4];
  {
    const float mu = stat[1];
    const int gr = 96 + rA + m;
    float xl = serD[gr-1];
    float xc = serD[gr];
    float xr = (gr == LD-1) ? (serD[0] - mu) : serD[gr+1];
    convT(xt, p.dec_conv_w, xl, xc, xr, q);
  }
  kvT2(xA, xB, rA, rB, Kf, Vt, dWk_t, p.dbk, dWv_t, p.dbv, lane, m, q);
  __syncthreads();                       // B5: dec K/V visible
  // ---- P5: decoder (all 3 waves, one tile each) ----
  {
    attnT(xt, Kf, Vt, dWq_t, qbD, dWo_t, p.dbo, p.dn2_g, p.dn2_b, lane, m, q);
    // FFN d->4d->d, 4 hidden chunks; acc C-init with dc2_b (bias once)
    f4 acc[4];
    #pragma unroll
    for (int nt = 0; nt < 4; ++nt) acc[nt] = *(const f4*)(p.dc2_b + nt*16 + d0);
    for (int cc2 = 0; cc2 < 4; ++cc2){
      f4 hh[4];
      mm64T(dc1f + cc2*4096, xt, hh, lane, p.dc1_b + cc2*64, d0);
      h4 ht[4];
      #pragma unroll
      for (int nt = 0; nt < 4; ++nt) ht[nt] = relu_pk(hh[nt]);
      #pragma unroll
      for (int nt = 0; nt < 4; ++nt){
        const _Float16* ar = dc2f + cc2*4096 + (nt*128 + lane)*8;
        h8 w0 = *(const h8*)(ar);
        h8 w1 = *(const h8*)(ar + 512);
        acc[nt] = MFMA4(lo4(w0), ht[0], acc[nt]);
        acc[nt] = MFMA4(hi4(w0), ht[1], acc[nt]);
        acc[nt] = MFMA4(lo4(w1), ht[2], acc[nt]);
        acc[nt] = MFMA4(hi4(w1), ht[3], acc[nt]);
      }
    }
    // final LN(dn3) + proj + enc-mean
    f4 vf[4];
    #pragma unroll
    for (int nt = 0; nt < 4; ++nt){
      #pragma unroll
      for (int i = 0; i < 4; ++i) vf[nt][i] = acc[nt][i] + (float)xt[nt][i];
    }
    float s = 0.f, s2 = 0.f;
    #pragma unroll
    for (int nt = 0; nt < 4; ++nt)
      #pragma unroll
      for (int i = 0; i < 4; ++i){ float v = vf[nt][i]; s += v; s2 = fmaf(v, v, s2); }
    s = q_sum(s); s2 = q_sum(s2);
    float mu = s * (1.f/64.f);
    float rs = rsqrtf(fmaxf(s2 * (1.f/64.f) - mu*mu, 0.f) + 1e-5f);
    float pp = 0.f;
    #pragma unroll
    for (int nt = 0; nt < 4; ++nt){
      f4 g4 = *(const f4*)(p.dn3_g + nt*16 + d0);
      f4 b4 = *(const f4*)(p.dn3_b + nt*16 + d0);
      f4 w4 = *(const f4*)(p.proj_w + nt*16 + d0);
      #pragma unroll
      for (int i = 0; i < 4; ++i)
        pp += ((vf[nt][i]-mu)*rs*g4[i] + b4[i]) * w4[i];
    }
    pp = q_sum(pp);
    if (q == 0)
      p.out[(b*OUTL + rA + m)*NNODE + n] = pp + p.proj_b[0] + stat[0];
  }
}

extern "C" void kernel_launch(void* const* d_in, const int* in_sizes, int n_in,
                              void* d_out, int out_size, void* d_ws, size_t ws_size,
                              hipStream_t stream) {
  Params p;
  p.x_enc = (const float*)d_in[0];  p.x_dec = (const float*)d_in[1];
  p.enc_conv_w = (const float*)d_in[4];  p.dec_conv_w = (const float*)d_in[5];
  p.eWq = (const float*)d_in[6];   p.ebq = (const float*)d_in[7];
  p.eWk = (const float*)d_in[8];   p.ebk = (const float*)d_in[9];
  p.eWv = (const float*)d_in[10];  p.ebv = (const float*)d_in[11];
  p.eWo = (const float*)d_in[12];  p.ebo = (const float*)d_in[13];
  p.ec1_w = (const float*)d_in[14]; p.ec1_b = (const float*)d_in[15];
  p.ec2_w = (const float*)d_in[16]; p.ec2_b = (const float*)d_in[17];
  p.en1_g = (const float*)d_in[18]; p.en1_b = (const float*)d_in[19];
  p.en2_g = (const float*)d_in[20]; p.en2_b = (const float*)d_in[21];
  p.dWq = (const float*)d_in[22];  p.dbq = (const float*)d_in[23];
  p.dWk = (const float*)d_in[24];  p.dbk = (const float*)d_in[25];
  p.dWv = (const float*)d_in[26];  p.dbv = (const float*)d_in[27];
  p.dWo = (const float*)d_in[28];  p.dbo = (const float*)d_in[29];
  p.dc1_w = (const float*)d_in[30]; p.dc1_b = (const float*)d_in[31];
  p.dc2_w = (const float*)d_in[32]; p.dc2_b = (const float*)d_in[33];
  p.dn2_g = (const float*)d_in[34]; p.dn2_b = (const float*)d_in[35];
  p.dn3_g = (const float*)d_in[36]; p.dn3_b = (const float*)d_in[37];
  p.proj_w = (const float*)d_in[38]; p.proj_b = (const float*)d_in[39];
  p.out = (float*)d_out;

  _Float16* ws = (_Float16*)d_ws;
  prep_weights<<<144, 512, 0, stream>>>(p, ws);
  GraphTransformer_90237262889124_kernel<<<NSEQ, NTHR, 0, stream>>>(p, ws);
}